// Round 3
// baseline (1234.133 us; speedup 1.0000x reference)
//
#include <hip/hip_runtime.h>
#include <cstdint>
#include <cmath>

// ---------------------------------------------------------------------------
// PiT forward on MI355X. fp32 I/O; dense GEMMs via split-fp16 (hi+lo) MFMA
// (3 MFMAs per tile, ~fp32 accuracy); attention GEMMs use fp16-hi E with
// rowsum computed from the *rounded* E (error cancels in the softmax avg),
// 2 MFMAs per tile. All GEMMs N=256. Grid=512 blocks (2 blocks/CU) for
// latency hiding; B staged via global_load_lds width=16.
// ---------------------------------------------------------------------------

typedef _Float16 half8 __attribute__((ext_vector_type(8)));
typedef float f32x4 __attribute__((ext_vector_type(4)));

__device__ __forceinline__ float gelu_f(float x) {
  float u = 0.7978845608028654f * (x + 0.044715f * x * x * x);
  float a = __expf(2.0f * fabsf(u));
  float t = 1.0f - 2.0f / (a + 1.0f);   // tanh(|u|), inf-safe
  t = (u < 0.0f) ? -t : t;
  return 0.5f * x * (1.0f + t);
}

__device__ __forceinline__ void cvt_hilo(float4 a, float4 b, half8& h, half8& l) {
  h[0] = (_Float16)a.x; l[0] = (_Float16)(a.x - (float)h[0]);
  h[1] = (_Float16)a.y; l[1] = (_Float16)(a.y - (float)h[1]);
  h[2] = (_Float16)a.z; l[2] = (_Float16)(a.z - (float)h[2]);
  h[3] = (_Float16)a.w; l[3] = (_Float16)(a.w - (float)h[3]);
  h[4] = (_Float16)b.x; l[4] = (_Float16)(b.x - (float)h[4]);
  h[5] = (_Float16)b.y; l[5] = (_Float16)(b.y - (float)h[5]);
  h[6] = (_Float16)b.z; l[6] = (_Float16)(b.z - (float)h[6]);
  h[7] = (_Float16)b.w; l[7] = (_Float16)(b.w - (float)h[7]);
}

// async 16B global->LDS (lane i -> ldsbase + i*16). C-style addrspace casts
// (generic -> AS(1)/AS(3)) lower to addrspacecast in clang/HIP.
typedef __attribute__((address_space(3))) unsigned int lds_u32;
typedef __attribute__((address_space(1))) unsigned int gbl_u32;
__device__ __forceinline__ void ldsdma16(const void* g, void* l) {
  __builtin_amdgcn_global_load_lds((const gbl_u32*)g, (lds_u32*)l, 16, 0, 0);
}

// ---------------------------------------------------------------------------
// Unified GEMM: C[M,256] = A[M,K] (or E=exp(scale*(rm-md))) @ B[K,256]
// B = fp16 hi/lo planes [head][col(256)][k]. LDS: A row-major pitch 40,
// B [kq][col][8] (DMA-compatible). Waves: w covers cols [w*64, w*64+64).
// EPI: 0 C+b; 1 gelu(C+b); 2 gelu(C+b+add); 3 V-plane split write;
//      4 fused att epilogue gelu(C/rowsum) (nkb==1 only); 5 split-K partials.
// bid = ((head*njb + jb)*nkb + kb)*ncb + cb.
// ---------------------------------------------------------------------------
template <int BM, int BN, bool IS_ATT, int EPI>
__global__ void __launch_bounds__(BN, 2)
gemm2_k(const float* __restrict__ A, const _Float16* __restrict__ Bhi,
        const _Float16* __restrict__ Blo, const float* __restrict__ bias,
        const float* __restrict__ addbuf, const float* __restrict__ rowmin,
        const float* __restrict__ r_arr, float* __restrict__ outp,
        _Float16* __restrict__ Vhi, _Float16* __restrict__ Vlo,
        float* __restrict__ Cpart, float* __restrict__ Spart,
        int K, int KC, int Mh, int njb, int ncb, int nkb, int Mtot,
        int NB, int bshift) {
  constexpr int MT = BM / 16;
  constexpr int AP = 40;  // halves; 80B rows -> 16B aligned frags, <=2-way banks
  __shared__ __align__(16) _Float16 AhS[BM * AP];
  __shared__ __align__(16) _Float16 AlS[IS_ATT ? 8 : BM * AP];
  __shared__ __align__(16) _Float16 BhS[4 * BN * 8];
  __shared__ __align__(16) _Float16 BlS[4 * BN * 8];
  __shared__ float esumS[IS_ATT ? BM * 4 : 4];

  const int t = threadIdx.x;
  const int lane = t & 63;
  const int w = t >> 6;
  int tmp = blockIdx.x;
  const int cb = tmp % ncb; tmp /= ncb;
  const int kb = tmp % nkb; tmp /= nkb;
  const int jb = tmp % njb;
  const int head = tmp / njb;

  const int arow = t >> 2, aq = t & 3;            // A staging: 4 thr/row
  const bool astage = (t < BM * 4);
  const float* aptr = A + (size_t)(head * Mh + jb * BM + (astage ? arow : 0)) * K
                        + kb * KC + aq * 8;

  float scale = 0.f, rm = 0.f;
  if constexpr (IS_ATT) {
    float rv = r_arr[head];
    const float c0 = (float)(0.25 * 3.14159265358979323846 * (1.0 - 1e-07));
    scale = tanf(c0 * (1.0f + sinf(rv)));
    rm = rowmin[head * Mh + jb * BM + (astage ? arow : 0)];
  }

  const int bcol = cb * BN + w * 64 + lane;       // this lane's B column
  const _Float16* bph = Bhi + (size_t)(head * 256 + bcol) * K + kb * KC;
  const _Float16* bpl = Blo + (size_t)(head * 256 + bcol) * K + kb * KC;

  f32x4 acc[MT][4];
#pragma unroll
  for (int i = 0; i < MT; i++)
#pragma unroll
    for (int j = 0; j < 4; j++) acc[i][j] = (f32x4){0.f, 0.f, 0.f, 0.f};

  float esum_part = 0.f;
  const int lm = lane & 15, kq = lane >> 4;

#pragma unroll 1
  for (int kt = 0; kt < KC; kt += 32) {
    // ---- B: async DMA, wave w stages its own 64 cols, [kq][col][8] ----
#pragma unroll
    for (int kg = 0; kg < 4; kg++) {
      ldsdma16(bph + kt + kg * 8, &BhS[(size_t)(kg * BN + w * 64) * 8]);
      ldsdma16(bpl + kt + kg * 8, &BlS[(size_t)(kg * BN + w * 64) * 8]);
    }
    // ---- A: registers (exp / hi-lo split) -> LDS ----
    if (astage) {
      const float* ap = aptr + kt;
      float4 v0 = *(const float4*)ap;
      float4 v1 = *(const float4*)(ap + 4);
      if constexpr (IS_ATT) {
        half8 h;
        float va[8] = {v0.x, v0.y, v0.z, v0.w, v1.x, v1.y, v1.z, v1.w};
#pragma unroll
        for (int j = 0; j < 8; j++) {
          float e = __expf(scale * (rm - va[j]));
          h[j] = (_Float16)e;
          esum_part += (float)h[j];   // rowsum of ROUNDED E (error cancels)
        }
        *(half8*)&AhS[arow * AP + aq * 8] = h;
      } else {
        half8 h, l;
        cvt_hilo(v0, v1, h, l);
        *(half8*)&AhS[arow * AP + aq * 8] = h;
        *(half8*)&AlS[arow * AP + aq * 8] = l;
      }
    }
    __syncthreads();
    // ---- fragments + MFMA ----
    half8 fbh[4], fbl[4];
#pragma unroll
    for (int nt = 0; nt < 4; nt++) {
      fbh[nt] = *(const half8*)&BhS[(size_t)(kq * BN + w * 64 + nt * 16 + lm) * 8];
      fbl[nt] = *(const half8*)&BlS[(size_t)(kq * BN + w * 64 + nt * 16 + lm) * 8];
    }
#pragma unroll
    for (int mt = 0; mt < MT; mt++) {
      half8 fah = *(const half8*)&AhS[(mt * 16 + lm) * AP + kq * 8];
      half8 fal;
      if constexpr (!IS_ATT) fal = *(const half8*)&AlS[(mt * 16 + lm) * AP + kq * 8];
#pragma unroll
      for (int nt = 0; nt < 4; nt++) {
        if constexpr (!IS_ATT)
          acc[mt][nt] = __builtin_amdgcn_mfma_f32_16x16x32_f16(fal, fbh[nt], acc[mt][nt], 0, 0, 0);
        acc[mt][nt] = __builtin_amdgcn_mfma_f32_16x16x32_f16(fah, fbl[nt], acc[mt][nt], 0, 0, 0);
        acc[mt][nt] = __builtin_amdgcn_mfma_f32_16x16x32_f16(fah, fbh[nt], acc[mt][nt], 0, 0, 0);
      }
    }
    __syncthreads();
  }

  if constexpr (IS_ATT) {
    if (astage) esumS[t] = esum_part;
    __syncthreads();
  }

  // ---- epilogue: C/D layout col=lane&15, row=(lane>>4)*4+reg ----
#pragma unroll
  for (int mt = 0; mt < MT; mt++) {
    float rs[4];
    if constexpr (EPI == 4) {
#pragma unroll
      for (int r = 0; r < 4; r++) {
        int rl = mt * 16 + kq * 4 + r;
        rs[r] = (esumS[rl * 4] + esumS[rl * 4 + 1]) +
                (esumS[rl * 4 + 2] + esumS[rl * 4 + 3]);
      }
    }
#pragma unroll
    for (int nt = 0; nt < 4; nt++) {
      const int col = cb * BN + w * 64 + nt * 16 + lm;
      float bv = 0.f;
      if constexpr (EPI <= 2) bv = bias[col];
#pragma unroll
      for (int r = 0; r < 4; r++) {
        const int rl = mt * 16 + kq * 4 + r;
        const int rlocal = jb * BM + rl;
        float c = acc[mt][nt][r];
        if constexpr (EPI == 0) {
          outp[(size_t)rlocal * 256 + col] = c + bv;
        } else if constexpr (EPI == 1) {
          outp[(size_t)rlocal * 256 + col] = gelu_f(c + bv);
        } else if constexpr (EPI == 2) {
          outp[(size_t)rlocal * 256 + col] =
              gelu_f(c + bv + addbuf[(size_t)rlocal * 256 + col]);
        } else if constexpr (EPI == 3) {
          int hh = col >> 5, vv = col & 31;
          int b = rlocal >> bshift, n = rlocal & (NB - 1);
          size_t idx = ((size_t)(hh * 256 + b * 32 + vv)) * (size_t)NB + n;
          _Float16 hv = (_Float16)c;
          Vhi[idx] = hv;
          Vlo[idx] = (_Float16)(c - (float)hv);
        } else if constexpr (EPI == 4) {
          float g = gelu_f(c / rs[r]);
          int b = col >> 5, vd = col & 31;
          outp[(size_t)b * NB * 256 + (size_t)rlocal * 256 + head * 32 + vd] = g;
        } else {  // EPI == 5: split-K partial
          Cpart[((size_t)kb * Mtot + head * Mh + rlocal) * 256 + col] = c;
        }
      }
    }
  }
  if constexpr (EPI == 5) {
    if (t < BM)
      Spart[(size_t)kb * Mtot + head * Mh + jb * BM + t] =
          (esumS[t * 4] + esumS[t * 4 + 1]) + (esumS[t * 4 + 2] + esumS[t * 4 + 3]);
  }
}

// ---- split-K att reduce: out[b][n][head*32+vd] = gelu(sum C / sum S) ------
template <int KB>
__global__ void att_reduce_k(const float* __restrict__ Cpart,
                             const float* __restrict__ Spart,
                             float* __restrict__ outp, int Mtot) {
  int gid = blockIdx.x * 256 + threadIdx.x;
  int row = gid >> 6;
  int c4 = (gid & 63) << 2;
  float4 c = *(const float4*)&Cpart[(size_t)row * 256 + c4];
  float s = Spart[row];
#pragma unroll
  for (int kb = 1; kb < KB; kb++) {
    float4 d = *(const float4*)&Cpart[((size_t)kb * Mtot + row) * 256 + c4];
    c.x += d.x; c.y += d.y; c.z += d.z; c.w += d.w;
    s += Spart[(size_t)kb * Mtot + row];
  }
  float inv = 1.0f / s;
  float4 g;
  g.x = gelu_f(c.x * inv); g.y = gelu_f(c.y * inv);
  g.z = gelu_f(c.z * inv); g.w = gelu_f(c.w * inv);
  int head = row >> 10, n = row & 1023;
  int b = c4 >> 5, vd = c4 & 31;
  *(float4*)&outp[((size_t)b * 1024 + n) * 256 + head * 32 + vd] = g;
}

// ---------------------------------------------------------------------------
// Small kernels
// ---------------------------------------------------------------------------
struct PrepArgs { const float* src[11]; };

__global__ void prep_k(PrepArgs pa, _Float16* __restrict__ wt) {
  int mat = blockIdx.x >> 8;
  int o = ((blockIdx.x & 255) << 8) | threadIdx.x;  // n*256+k
  int n = o >> 8, k = o & 255;
  const float* s = pa.src[mat];
  float v = (mat < 4) ? s[((n >> 5) << 13) + (k << 5) + (n & 31)]
                      : s[(k << 8) + n];
  _Float16* hi = wt + (size_t)mat * 131072;
  _Float16 hv = (_Float16)v;
  hi[o] = hv;
  hi[65536 + o] = (_Float16)(v - (float)hv);
}

__global__ void rowmin_k(const float* __restrict__ d0, const float* __restrict__ d1,
                         const float* __restrict__ d2, const float* __restrict__ d3,
                         float* __restrict__ out) {
  int wavg = blockIdx.x * 4 + (threadIdx.x >> 6);
  int lane = threadIdx.x & 63;
  const float* src; int len; int row; float* o;
  if (wavg < 8192)       { src = d0; len = 4096; row = wavg;         o = out; }
  else if (wavg < 16384) { src = d1; len = 1024; row = wavg - 8192;  o = out + 8192; }
  else if (wavg < 24576) { src = d2; len = 1024; row = wavg - 16384; o = out + 16384; }
  else                   { src = d3; len = 1024; row = wavg - 24576; o = out + 24576; }
  const float4* p = (const float4*)(src + (size_t)row * len);
  float m = 1e30f;
  for (int i = lane, e = len >> 2; i < e; i += 64) {
    float4 v = p[i];
    m = fminf(m, fminf(fminf(v.x, v.y), fminf(v.z, v.w)));
  }
#pragma unroll
  for (int o2 = 32; o2; o2 >>= 1) m = fminf(m, __shfl_xor(m, o2));
  if (lane == 0) o[row] = m;
}

__global__ void encoder_k(const float* __restrict__ x, const float* __restrict__ w,
                          const float* __restrict__ b, float* __restrict__ out) {
  int id = blockIdx.x * 256 + threadIdx.x;
  int m = id >> 6;
  int c4 = (id & 63) << 2;
  float4 xv = *(const float4*)(x + (size_t)m * 4);
  float4 w0 = *(const float4*)(w + c4);
  float4 w1 = *(const float4*)(w + 256 + c4);
  float4 w2 = *(const float4*)(w + 512 + c4);
  float4 w3 = *(const float4*)(w + 768 + c4);
  float4 bb = *(const float4*)(b + c4);
  float4 o;
  o.x = gelu_f(bb.x + xv.x * w0.x + xv.y * w1.x + xv.z * w2.x + xv.w * w3.x);
  o.y = gelu_f(bb.y + xv.x * w0.y + xv.y * w1.y + xv.z * w2.y + xv.w * w3.y);
  o.z = gelu_f(bb.z + xv.x * w0.z + xv.y * w1.z + xv.z * w2.z + xv.w * w3.z);
  o.w = gelu_f(bb.w + xv.x * w0.w + xv.y * w1.w + xv.z * w2.w + xv.w * w3.w);
  *(float4*)(out + (size_t)m * 256 + c4) = o;
}

__global__ void defc2_k(const float* __restrict__ h, const float* __restrict__ w,
                        const float* __restrict__ b, float* __restrict__ out) {
  int lane = threadIdx.x & 63;
  int wv = threadIdx.x >> 6;
  float4 wf = *(const float4*)(w + lane * 4);
  float bias = b[0];
  for (int row = blockIdx.x * 4 + wv; row < 32768; row += gridDim.x * 4) {
    float4 hv = *(const float4*)(h + (size_t)row * 256 + lane * 4);
    float d = hv.x * wf.x + hv.y * wf.y + hv.z * wf.z + hv.w * wf.w;
#pragma unroll
    for (int o = 32; o; o >>= 1) d += __shfl_xor(d, o);
    if (lane == 0) out[row] = d + bias;
  }
}

// ---------------------------------------------------------------------------
extern "C" void kernel_launch(void* const* d_in, const int* in_sizes, int n_in,
                              void* d_out, int out_size, void* d_ws, size_t ws_size,
                              hipStream_t stream) {
  (void)in_sizes; (void)n_in; (void)out_size; (void)ws_size;
  const float* x       = (const float*)d_in[0];
  const float* md_down = (const float*)d_in[1];
  const float* md_p0   = (const float*)d_in[2];
  const float* md_p1   = (const float*)d_in[3];
  const float* md_up   = (const float*)d_in[4];
  const float* en_w    = (const float*)d_in[5];
  const float* en_b    = (const float*)d_in[6];
  const float* down_r  = (const float*)d_in[7];
  const float* up_r    = (const float*)d_in[25];
  const float* de1_b   = (const float*)d_in[28];
  const float* de2_w   = (const float*)d_in[29];
  const float* de2_b   = (const float*)d_in[30];

  const float* pr[2]   = {(const float*)d_in[9],  (const float*)d_in[17]};
  const float* md_p[2] = {md_p0, md_p1};
  const float* f1b[2]  = {(const float*)d_in[12], (const float*)d_in[20]};
  const float* f2b[2]  = {(const float*)d_in[14], (const float*)d_in[22]};
  const float* rbb[2]  = {(const float*)d_in[16], (const float*)d_in[24]};
  int wt_pa[2] = {1, 2}, wtf1[2] = {4, 7}, wtf2[2] = {5, 8}, wtr[2] = {6, 9};

  // ---- workspace layout (~137.4 MB) ----
  char* ws = (char*)d_ws;
  size_t off = 0;
  auto alloc = [&](size_t bytes) -> void* {
    void* p = ws + off;
    off += (bytes + 255) & ~(size_t)255;
    return p;
  };
  _Float16* wt   = (_Float16*)alloc((size_t)11 * 131072 * 2);  // hi/lo planes
  float* rowmin  = (float*)alloc((size_t)57344 * 4);
  float* hfa     = (float*)alloc((size_t)33554432);   // [8,4096,256]; also Cpart
  float* hfb     = (float*)alloc((size_t)33554432);
  float* hl_h    = (float*)alloc((size_t)8388608);    // [8,1024,256] latent state
  float* hl_pa   = (float*)alloc((size_t)8388608);
  float* hl_t1   = (float*)alloc((size_t)8388608);
  float* hl_r    = (float*)alloc((size_t)8388608);
  _Float16* Vhi  = (_Float16*)alloc((size_t)16777216);
  _Float16* Vlo  = (_Float16*)alloc((size_t)16777216);
  float* Spart   = (float*)alloc((size_t)4 * 8192 * 4);
  float* Cpart   = hfa;      // hfa dead after value_down consumes it
  float* de1_out = hl_h;     // hl_h..hl_r contiguous 33.5MB, dead by de_fc1

  auto WT_HI = [&](int m) { return wt + (size_t)m * 131072; };
  auto WT_LO = [&](int m) { return wt + (size_t)m * 131072 + 65536; };

  PrepArgs pa;
  pa.src[0] = (const float*)d_in[8];   // down_w (headcat)
  pa.src[1] = (const float*)d_in[10];  // pa0_w  (headcat)
  pa.src[2] = (const float*)d_in[18];  // pa1_w  (headcat)
  pa.src[3] = (const float*)d_in[26];  // up_w   (headcat)
  pa.src[4] = (const float*)d_in[11];  // mlp0_fc1_w
  pa.src[5] = (const float*)d_in[13];  // mlp0_fc2_w
  pa.src[6] = (const float*)d_in[15];  // res0_w
  pa.src[7] = (const float*)d_in[19];  // mlp1_fc1_w
  pa.src[8] = (const float*)d_in[21];  // mlp1_fc2_w
  pa.src[9] = (const float*)d_in[23];  // res1_w
  pa.src[10] = (const float*)d_in[27]; // de_fc1_w

  prep_k<<<2816, 256, 0, stream>>>(pa, wt);
  rowmin_k<<<14336, 256, 0, stream>>>(md_down, md_p0, md_p1, md_up, rowmin);
  encoder_k<<<8192, 256, 0, stream>>>(x, en_w, en_b, hfa);

  // value_down: [32768,256]@[256,256] -> V planes, NB=4096
  gemm2_k<64, 256, false, 3><<<512, 256, 0, stream>>>(
      hfa, WT_HI(0), WT_LO(0), nullptr, nullptr, nullptr, nullptr, nullptr,
      Vhi, Vlo, nullptr, nullptr, 256, 256, 32768, 512, 1, 1, 32768, 4096, 12);
  // att_down: per head [1024,4096]@[4096,256], split-K x4 -> partials
  gemm2_k<64, 256, true, 5><<<512, 256, 0, stream>>>(
      md_down, Vhi, Vlo, nullptr, nullptr, rowmin, down_r, nullptr,
      nullptr, nullptr, Cpart, Spart, 4096, 1024, 1024, 16, 1, 4, 8192, 0, 0);
  att_reduce_k<4><<<2048, 256, 0, stream>>>(Cpart, Spart, hl_h, 8192);

  for (int i = 0; i < 2; i++) {
    gemm2_k<32, 128, false, 3><<<512, 128, 0, stream>>>(
        hl_h, WT_HI(wt_pa[i]), WT_LO(wt_pa[i]), nullptr, nullptr, nullptr,
        nullptr, nullptr, Vhi, Vlo, nullptr, nullptr,
        256, 256, 8192, 256, 2, 1, 8192, 1024, 10);
    gemm2_k<32, 256, true, 5><<<512, 256, 0, stream>>>(
        md_p[i], Vhi, Vlo, nullptr, nullptr, rowmin + 8192 + i * 8192, pr[i],
        nullptr, nullptr, nullptr, Cpart, Spart,
        1024, 512, 1024, 32, 1, 2, 8192, 0, 0);
    att_reduce_k<2><<<2048, 256, 0, stream>>>(Cpart, Spart, hl_pa, 8192);
    gemm2_k<32, 128, false, 1><<<512, 128, 0, stream>>>(
        hl_pa, WT_HI(wtf1[i]), WT_LO(wtf1[i]), f1b[i], nullptr, nullptr,
        nullptr, hl_t1, nullptr, nullptr, nullptr, nullptr,
        256, 256, 8192, 256, 2, 1, 8192, 0, 0);
    gemm2_k<32, 128, false, 0><<<512, 128, 0, stream>>>(
        hl_h, WT_HI(wtr[i]), WT_LO(wtr[i]), rbb[i], nullptr, nullptr,
        nullptr, hl_r, nullptr, nullptr, nullptr, nullptr,
        256, 256, 8192, 256, 2, 1, 8192, 0, 0);
    gemm2_k<32, 128, false, 2><<<512, 128, 0, stream>>>(
        hl_t1, WT_HI(wtf2[i]), WT_LO(wtf2[i]), f2b[i], hl_r, nullptr,
        nullptr, hl_h, nullptr, nullptr, nullptr, nullptr,
        256, 256, 8192, 256, 2, 1, 8192, 0, 0);
  }

  // value_up
  gemm2_k<32, 128, false, 3><<<512, 128, 0, stream>>>(
      hl_h, WT_HI(3), WT_LO(3), nullptr, nullptr, nullptr, nullptr, nullptr,
      Vhi, Vlo, nullptr, nullptr, 256, 256, 8192, 256, 2, 1, 8192, 1024, 10);
  // att_up: per head [4096,1024]@[1024,256], fused epilogue -> hfb
  gemm2_k<64, 256, true, 4><<<512, 256, 0, stream>>>(
      md_up, Vhi, Vlo, nullptr, nullptr, rowmin + 24576, up_r, hfb,
      nullptr, nullptr, nullptr, nullptr, 1024, 1024, 4096, 64, 1, 1, 32768, 4096, 0);
  // de_fc1
  gemm2_k<64, 256, false, 1><<<512, 256, 0, stream>>>(
      hfb, WT_HI(10), WT_LO(10), de1_b, nullptr, nullptr, nullptr, de1_out,
      nullptr, nullptr, nullptr, nullptr, 256, 256, 32768, 512, 1, 1, 32768, 0, 0);
  defc2_k<<<1024, 256, 0, stream>>>(de1_out, de2_w, de2_b, (float*)d_out);
}